// Round 5
// baseline (15190.579 us; speedup 1.0000x reference)
//
#include <hip/hip_runtime.h>
#include <cstdint>
#include <cstddef>

#define B_ 32
#define T_ 2048
#define I_ 256
#define H_ 512
#define G_ 16
#define SLICE (H_/G_)   // 32 h_out columns per workgroup

typedef float  f32x4  __attribute__((ext_vector_type(4)));
typedef __bf16 bf16x8 __attribute__((ext_vector_type(8)));

__device__ __forceinline__ f32x4 MFMA(bf16x8 a, bf16x8 b, f32x4 c) {
    return __builtin_amdgcn_mfma_f32_16x16x32_bf16(a, b, c, 0, 0, 0);
}

__device__ __forceinline__ bf16x8 cvt8v(float4 a, float4 b) {
    bf16x8 r;
    r[0] = (__bf16)a.x; r[1] = (__bf16)a.y; r[2] = (__bf16)a.z; r[3] = (__bf16)a.w;
    r[4] = (__bf16)b.x; r[5] = (__bf16)b.y; r[6] = (__bf16)b.z; r[7] = (__bf16)b.w;
    return r;
}

// xu partial for one wave: A = x rows (16 batches) x K=256, B = u_w slice frags.
__device__ __forceinline__ f32x4 xu_step(const float* xp, const bf16x8 uf[8]) {
    float4 xr[16];
#pragma unroll
    for (int kc = 0; kc < 8; ++kc) {
        xr[2*kc]   = *(const float4*)(xp + kc*32);
        xr[2*kc+1] = *(const float4*)(xp + kc*32 + 4);
    }
    f32x4 a = {0.f, 0.f, 0.f, 0.f};
#pragma unroll
    for (int kc = 0; kc < 8; ++kc)
        a = MFMA(cvt8v(xr[2*kc], xr[2*kc+1]), uf[kc], a);
    return a;
}

// Persistent scan kernel. G_ workgroups x 512 threads.
// Waves 0-3: recurrence GEMM (h @ w_w^T) for (m-half, n-half); w_w slice in regs.
// Waves 4-7: x-projection (x_t @ u_w^T) one step ahead; u_w slice in regs.
__global__ __launch_bounds__(512, 1) void rnn_scan(
    const float* __restrict__ x, const float* __restrict__ u_w,
    const float* __restrict__ u_b, const float* __restrict__ w_w,
    const float* __restrict__ w_b, __bf16* __restrict__ hs /* = d_out as bf16 */,
    __bf16* hbuf /* ws: 2 x B_ x H_ */, unsigned* bar /* ws: cnt @0, flag @+128B */)
{
    const int tid = threadIdx.x;
    const int wv  = tid >> 6;
    const int ln  = tid & 63;
    const int l15 = ln & 15, lq = ln >> 4;
    const int base = blockIdx.x * SLICE;

    __shared__ f32x4 xup[4][64];

    unsigned* cnt  = bar;
    unsigned* flag = bar + 32;   // separate cacheline

    if (wv < 4) {
        const int mh = wv >> 1, nh = wv & 1;
        const int ho = base + nh*16 + l15;          // this lane's output column
        // persistent w_w fragments: B[k][n] from row-major w_w[ho][k]
        bf16x8 wf[16];
#pragma unroll
        for (int kc = 0; kc < 16; ++kc) {
            const float* p = w_w + (size_t)ho*H_ + kc*32 + lq*8;
            wf[kc] = cvt8v(*(const float4*)p, *(const float4*)(p+4));
        }
        const float bias = u_b[ho] + w_b[ho];
        const int arow  = mh*16 + l15;   // A-fragment row (batch index)
        const int crow0 = mh*16 + lq*4;  // C rows base (batch index)

        for (int t = 0; t < T_; ++t) {
            const __bf16* cur = hbuf + (size_t)(t & 1) * (B_*H_);
            const __bf16* ap  = cur + (size_t)arow*H_ + lq*8;
            f32x4 acc0 = {0.f,0.f,0.f,0.f}, acc1 = {0.f,0.f,0.f,0.f};
#pragma unroll
            for (int kc = 0; kc < 16; kc += 2) {
                bf16x8 a0 = *(const bf16x8*)(ap + kc*32);
                bf16x8 a1 = *(const bf16x8*)(ap + (kc+1)*32);
                acc0 = MFMA(a0, wf[kc],   acc0);
                acc1 = MFMA(a1, wf[kc+1], acc1);
            }
            __syncthreads();                       // #1: xup(t) visible
            f32x4 xv = xup[wv][ln];
            __bf16* nxt = hbuf + (size_t)((t+1) & 1) * (B_*H_);
#pragma unroll
            for (int r = 0; r < 4; ++r) {
                float v = acc0[r] + acc1[r] + xv[r] + bias;
                float e = __expf(2.f * v);
                float h = 1.f - 2.f/(e + 1.f);     // tanh, saturates cleanly
                __bf16 hb = (__bf16)h;
                const int brow = crow0 + r;
                nxt[(size_t)brow*H_ + ho] = hb;
                hs[((size_t)brow*T_ + t)*H_ + ho] = hb;
            }
            __threadfence();                       // release: own writes → coherent point
            __syncthreads();                       // #2: whole WG's writes drained
            if (tid == 0) {
                unsigned old = atomicAdd(cnt, 1u);
                if (old == (unsigned)(G_*(t+1) - 1))
                    __hip_atomic_store(flag, (unsigned)(t+1),
                                       __ATOMIC_RELEASE, __HIP_MEMORY_SCOPE_AGENT);
                else
                    while (__hip_atomic_load(flag, __ATOMIC_ACQUIRE,
                                             __HIP_MEMORY_SCOPE_AGENT) < (unsigned)(t+1)) {}
                __threadfence();                   // acquire: invalidate L1/L2
            }
            __syncthreads();                       // #3: release whole WG
        }
    } else {
        const int wx = wv - 4, mh = wx >> 1, nh = wx & 1;
        const int ho = base + nh*16 + l15;
        bf16x8 uf[8];
#pragma unroll
        for (int kc = 0; kc < 8; ++kc) {
            const float* p = u_w + (size_t)ho*I_ + kc*32 + lq*8;
            uf[kc] = cvt8v(*(const float4*)p, *(const float4*)(p+4));
        }
        const int arow = mh*16 + l15;
        const float* xp0 = x + (size_t)arow*(T_*I_) + lq*8;
        f32x4 acc = xu_step(xp0, uf);              // xup(0)
        for (int t = 0; t < T_; ++t) {
            xup[wx][ln] = acc;                     // publish xup(t)
            __syncthreads();                       // #1
            const int tt = (t+1 < T_) ? (t+1) : (T_-1);
            acc = xu_step(xp0 + (size_t)tt*I_, uf);  // compute xup(t+1) in barrier window
            __threadfence();
            __syncthreads();                       // #2
            __syncthreads();                       // #3
        }
    }
}

__global__ void cvt_ow(const float* __restrict__ ow, __bf16* __restrict__ owb) {
    int i = blockIdx.x * blockDim.x + threadIdx.x;
    if (i < I_*H_) owb[i] = (__bf16)ow[i];
}

// Epilogue: out[bt, i] = sigmoid(hs[bt,:] @ o_w[i,:]^T + o_b[i]).
// Reads hs (bf16) from d_out and overwrites the same rows in place with fp32.
// RACE FIX: __syncthreads() between the load/MFMA phase and the stores —
// a fast wave's fp32 stores must not land in bytes a slower wave has not
// yet read as bf16 A-fragments (lower fp32 halves can alias bf16 NaN).
__global__ __launch_bounds__(256, 1) void out_proj(
    const __bf16* hs, const __bf16* __restrict__ owb,
    const float* __restrict__ o_b, float* out)
{
    const int tid = threadIdx.x, wv = tid >> 6, ln = tid & 63;
    const int l15 = ln & 15, lq = ln >> 4;
    const size_t m0 = (size_t)blockIdx.x * 32;
    const __bf16* a0p = hs + (m0 + l15)*H_ + lq*8;
    const __bf16* a1p = a0p + (size_t)16*H_;
    f32x4 acc[2][4] = {};
#pragma unroll
    for (int kc = 0; kc < 16; ++kc) {
        bf16x8 a0 = *(const bf16x8*)(a0p + kc*32);
        bf16x8 a1 = *(const bf16x8*)(a1p + kc*32);
#pragma unroll
        for (int nt = 0; nt < 4; ++nt) {
            const __bf16* bp = owb + (size_t)(wv*64 + nt*16 + l15)*H_ + kc*32 + lq*8;
            bf16x8 b = *(const bf16x8*)bp;
            acc[0][nt] = MFMA(a0, b, acc[0][nt]);
            acc[1][nt] = MFMA(a1, b, acc[1][nt]);
        }
    }
    __syncthreads();   // all waves' A-loads complete before any wave overwrites hs
#pragma unroll
    for (int nt = 0; nt < 4; ++nt) {
        const int col = wv*64 + nt*16 + l15;
        const float ob = o_b[col];
#pragma unroll
        for (int mt = 0; mt < 2; ++mt) {
#pragma unroll
            for (int r = 0; r < 4; ++r) {
                const size_t row = m0 + mt*16 + lq*4 + r;
                float v = acc[mt][nt][r] + ob;
                out[row*I_ + col] = 1.f/(1.f + __expf(-v));
            }
        }
    }
}

extern "C" void kernel_launch(void* const* d_in, const int* in_sizes, int n_in,
                              void* d_out, int out_size, void* d_ws, size_t ws_size,
                              hipStream_t stream)
{
    const float* x   = (const float*)d_in[0];
    const float* u_w = (const float*)d_in[1];
    const float* u_b = (const float*)d_in[2];
    const float* w_w = (const float*)d_in[3];
    const float* w_b = (const float*)d_in[4];
    const float* o_w = (const float*)d_in[5];
    const float* o_b = (const float*)d_in[6];

    char* ws = (char*)d_ws;
    __bf16*   hbuf = (__bf16*)ws;                  // 2 * 32 * 512 * 2B = 65536 B
    unsigned* bar  = (unsigned*)(ws + 65536);      // cnt @ +0, flag @ +128B (256 B region)
    __bf16*   owb  = (__bf16*)(ws + 65536 + 256);  // 256*512*2B = 262144 B

    // Re-arm barrier + zero h0 every launch (ws is poisoned before each timed call).
    hipMemsetAsync(d_ws, 0, 65536 + 256, stream);
    cvt_ow<<<dim3(512), dim3(256), 0, stream>>>(o_w, owb);
    rnn_scan<<<dim3(G_), dim3(512), 0, stream>>>(x, u_w, u_b, w_w, w_b,
                                                 (__bf16*)d_out, hbuf, bar);
    out_proj<<<dim3((B_*T_)/32), dim3(256), 0, stream>>>((const __bf16*)d_out, owb,
                                                         o_b, (float*)d_out);
}